// Round 4
// baseline (1269.856 us; speedup 1.0000x reference)
//
#include <hip/hip_runtime.h>

#define N_NODES 100000
#define N_EDGES 1600000
#define QNODES 25000      // nodes per src-quartile; u-slice = 25000*160B = 4 MB = per-XCD L2
#define NPASS 4
#define CAP_Q 24          // slots per (node, quartile); P(Poisson(4) >= 24) ~ 1e-11
#define NB1 391           // ceil(N_NODES/256)

typedef __attribute__((ext_vector_type(8))) short short8;
typedef __attribute__((ext_vector_type(4))) float floatx4;

__device__ inline short bf16_rne(float f) {
    union { float f; unsigned u; } v; v.f = f;
    unsigned r = v.u + 0x7FFF + ((v.u >> 16) & 1);
    return (short)(r >> 16);
}

// ---------------- weight prep: all transposed, bf16, zero-padded ----------------
__global__ __launch_bounds__(256) void wt_kernel(
    const float* __restrict__ Wb, const float* __restrict__ W1,
    const float* __restrict__ W2,
    short* __restrict__ WT, short* __restrict__ W1T, short* __restrict__ W2T)
{
    int i = blockIdx.x * 256 + threadIdx.x;
    if (i < 48 * 512) {
        int m = i >> 9, k = i & 511;
        WT[i] = bf16_rne((m < 40 && k < 500) ? Wb[k * 40 + m] : 0.f);
    }
    if (i < 64 * 64) {
        int m = i >> 6, k = i & 63;
        W1T[i] = bf16_rne((k < 40) ? W1[k * 64 + m] : 0.f);
    }
    if (i < 48 * 64) {
        int m = i >> 6, k = i & 63;
        W2T[i] = bf16_rne((m < 40) ? W2[k * 40 + m] : 0.f);
    }
}

// ---------------- scores = x @ W_base + b_base via MFMA ----------------
__global__ __launch_bounds__(256) void scores_kernel(
    const float* __restrict__ x, const short8* __restrict__ WT8,
    const float* __restrict__ bb, float* __restrict__ scores)
{
    int wave = threadIdx.x >> 6;
    int lane = threadIdx.x & 63;
    int n0 = (blockIdx.x * 4 + wave) * 16;
    if (n0 >= N_NODES) return;
    int n = n0 + (lane & 15);
    int quad = lane >> 4;
    int m = lane & 15;
    const float* xrow = x + (size_t)n * 500 + quad * 8;

    floatx4 acc0 = {0,0,0,0}, acc1 = {0,0,0,0}, acc2 = {0,0,0,0};

    #pragma unroll 5
    for (int ks = 0; ks < 15; ++ks) {
        int k0 = ks * 32;
        float4 xa = *(const float4*)(xrow + k0);
        float4 xb = *(const float4*)(xrow + k0 + 4);
        short8 bf;
        bf[0] = bf16_rne(xa.x); bf[1] = bf16_rne(xa.y);
        bf[2] = bf16_rne(xa.z); bf[3] = bf16_rne(xa.w);
        bf[4] = bf16_rne(xb.x); bf[5] = bf16_rne(xb.y);
        bf[6] = bf16_rne(xb.z); bf[7] = bf16_rne(xb.w);
        int widx = (k0 >> 3) + quad;
        short8 a0 = WT8[(size_t)(0  + m) * 64 + widx];
        short8 a1 = WT8[(size_t)(16 + m) * 64 + widx];
        short8 a2 = WT8[(size_t)(32 + m) * 64 + widx];
        acc0 = __builtin_amdgcn_mfma_f32_16x16x32_bf16(a0, bf, acc0, 0, 0, 0);
        acc1 = __builtin_amdgcn_mfma_f32_16x16x32_bf16(a1, bf, acc1, 0, 0, 0);
        acc2 = __builtin_amdgcn_mfma_f32_16x16x32_bf16(a2, bf, acc2, 0, 0, 0);
    }
    {   // K tail
        int kbase = 480 + quad * 8;
        float4 xa = {0,0,0,0}, xb = {0,0,0,0};
        if (kbase + 8 <= 500) { xa = *(const float4*)(xrow + 480); xb = *(const float4*)(xrow + 484); }
        else if (kbase < 500) { xa = *(const float4*)(xrow + 480); }
        short8 bf;
        bf[0] = bf16_rne(xa.x); bf[1] = bf16_rne(xa.y);
        bf[2] = bf16_rne(xa.z); bf[3] = bf16_rne(xa.w);
        bf[4] = bf16_rne(xb.x); bf[5] = bf16_rne(xb.y);
        bf[6] = bf16_rne(xb.z); bf[7] = bf16_rne(xb.w);
        int widx = 60 + quad;
        short8 a0 = WT8[(size_t)(0  + m) * 64 + widx];
        short8 a1 = WT8[(size_t)(16 + m) * 64 + widx];
        short8 a2 = WT8[(size_t)(32 + m) * 64 + widx];
        acc0 = __builtin_amdgcn_mfma_f32_16x16x32_bf16(a0, bf, acc0, 0, 0, 0);
        acc1 = __builtin_amdgcn_mfma_f32_16x16x32_bf16(a1, bf, acc1, 0, 0, 0);
        acc2 = __builtin_amdgcn_mfma_f32_16x16x32_bf16(a2, bf, acc2, 0, 0, 0);
    }

    float* srow = scores + (size_t)n * 40;
    int mb = quad * 4;
    float4 b4 = *(const float4*)(bb + mb);
    *(float4*)(srow + mb) = make_float4(acc0[0] + b4.x, acc0[1] + b4.y,
                                        acc0[2] + b4.z, acc0[3] + b4.w);
    mb = 16 + quad * 4;
    b4 = *(const float4*)(bb + mb);
    *(float4*)(srow + mb) = make_float4(acc1[0] + b4.x, acc1[1] + b4.y,
                                        acc1[2] + b4.z, acc1[3] + b4.w);
    mb = 32 + quad * 4;
    if (mb < 40) {
        b4 = *(const float4*)(bb + mb);
        *(float4*)(srow + mb) = make_float4(acc2[0] + b4.x, acc2[1] + b4.y,
                                            acc2[2] + b4.z, acc2[3] + b4.w);
    }
}

// ---------------- fused softmax + MLP via MFMA ----------------
// Node-major outputs: h0[node][40] = 0.1*h (alpha pre-folded),
//                     u0[node][40] = inv_out[node]*h (propagation state)
__global__ __launch_bounds__(320) void mlp_kernel(
    const float* __restrict__ scores,
    const short8* __restrict__ W1T8, const float* __restrict__ b1,
    const short8* __restrict__ W2T8, const float* __restrict__ b2,
    float* __restrict__ h0, float* __restrict__ u0,
    const float* __restrict__ inv_out)
{
    __shared__ short hs[5][16 * 72];
    int wave = threadIdx.x >> 6;
    int lane = threadIdx.x & 63;
    int q = lane >> 4;
    int n16 = lane & 15;
    int node = (blockIdx.x * 5 + wave) * 16 + n16;
    float iv = inv_out[node];

    const float* srow = scores + (size_t)node * 40;
    float4 xa = *(const float4*)(srow + q * 8);
    float4 xb = *(const float4*)(srow + q * 8 + 4);
    float4 xc = {0,0,0,0}, xd = {0,0,0,0};
    if (q == 0) { xc = *(const float4*)(srow + 32); xd = *(const float4*)(srow + 36); }

    float m = fmaxf(fmaxf(fmaxf(xa.x, xa.y), fmaxf(xa.z, xa.w)),
                    fmaxf(fmaxf(xb.x, xb.y), fmaxf(xb.z, xb.w)));
    if (q == 0)
        m = fmaxf(m, fmaxf(fmaxf(fmaxf(xc.x, xc.y), fmaxf(xc.z, xc.w)),
                           fmaxf(fmaxf(xd.x, xd.y), fmaxf(xd.z, xd.w))));
    m = fmaxf(m, __shfl_xor(m, 16));
    m = fmaxf(m, __shfl_xor(m, 32));

    float e0 = __expf(xa.x - m), e1 = __expf(xa.y - m), e2 = __expf(xa.z - m), e3 = __expf(xa.w - m);
    float e4 = __expf(xb.x - m), e5 = __expf(xb.y - m), e6 = __expf(xb.z - m), e7 = __expf(xb.w - m);
    float f0 = 0, f1 = 0, f2 = 0, f3 = 0, f4 = 0, f5 = 0, f6 = 0, f7 = 0;
    if (q == 0) {
        f0 = __expf(xc.x - m); f1 = __expf(xc.y - m); f2 = __expf(xc.z - m); f3 = __expf(xc.w - m);
        f4 = __expf(xd.x - m); f5 = __expf(xd.y - m); f6 = __expf(xd.z - m); f7 = __expf(xd.w - m);
    }
    float sum = e0 + e1 + e2 + e3 + e4 + e5 + e6 + e7 + f0 + f1 + f2 + f3 + f4 + f5 + f6 + f7;
    sum += __shfl_xor(sum, 16);
    sum += __shfl_xor(sum, 32);
    float inv = 1.f / sum;

    short8 bf_a, bf_b;
    bf_a[0] = bf16_rne(e0 * inv); bf_a[1] = bf16_rne(e1 * inv);
    bf_a[2] = bf16_rne(e2 * inv); bf_a[3] = bf16_rne(e3 * inv);
    bf_a[4] = bf16_rne(e4 * inv); bf_a[5] = bf16_rne(e5 * inv);
    bf_a[6] = bf16_rne(e6 * inv); bf_a[7] = bf16_rne(e7 * inv);
    bf_b[0] = bf16_rne(f0 * inv); bf_b[1] = bf16_rne(f1 * inv);
    bf_b[2] = bf16_rne(f2 * inv); bf_b[3] = bf16_rne(f3 * inv);
    bf_b[4] = bf16_rne(f4 * inv); bf_b[5] = bf16_rne(f5 * inv);
    bf_b[6] = bf16_rne(f6 * inv); bf_b[7] = bf16_rne(f7 * inv);

    short* hw = &hs[wave][0];
    #pragma unroll
    for (int t = 0; t < 4; ++t) {
        floatx4 acc = {0, 0, 0, 0};
        short8 A0 = W1T8[(t * 16 + n16) * 8 + q];
        short8 A1 = W1T8[(t * 16 + n16) * 8 + 4 + q];
        acc = __builtin_amdgcn_mfma_f32_16x16x32_bf16(A0, bf_a, acc, 0, 0, 0);
        acc = __builtin_amdgcn_mfma_f32_16x16x32_bf16(A1, bf_b, acc, 0, 0, 0);
        float4 bv = *(const float4*)(b1 + t * 16 + q * 4);
        short4 pk;
        pk.x = bf16_rne(fmaxf(acc[0] + bv.x, 0.f));
        pk.y = bf16_rne(fmaxf(acc[1] + bv.y, 0.f));
        pk.z = bf16_rne(fmaxf(acc[2] + bv.z, 0.f));
        pk.w = bf16_rne(fmaxf(acc[3] + bv.w, 0.f));
        *(short4*)(hw + n16 * 72 + t * 16 + q * 4) = pk;
    }
    __syncthreads();

    short8 h1a = *(const short8*)(hw + n16 * 72 + q * 8);
    short8 h1b = *(const short8*)(hw + n16 * 72 + 32 + q * 8);

    #pragma unroll
    for (int t = 0; t < 3; ++t) {
        floatx4 acc = {0, 0, 0, 0};
        short8 A0 = W2T8[(t * 16 + n16) * 8 + q];
        short8 A1 = W2T8[(t * 16 + n16) * 8 + 4 + q];
        acc = __builtin_amdgcn_mfma_f32_16x16x32_bf16(A0, h1a, acc, 0, 0, 0);
        acc = __builtin_amdgcn_mfma_f32_16x16x32_bf16(A1, h1b, acc, 0, 0, 0);
        int mc = t * 16 + q * 4;
        if (mc < 40) {
            float4 bv = *(const float4*)(b2 + mc);
            float rx = acc[0] + bv.x, ry = acc[1] + bv.y;
            float rz = acc[2] + bv.z, rw = acc[3] + bv.w;
            size_t idx = (size_t)node * 10 + t * 4 + q;   // node-major float4 slot
            ((float4*)h0)[idx] = make_float4(0.1f * rx, 0.1f * ry, 0.1f * rz, 0.1f * rw);
            ((float4*)u0)[idx] = make_float4(iv * rx, iv * ry, iv * rz, iv * rw);
        }
    }
}

// ---------------- fused degree count + quartile-bucketed CSR (no scan) ----------------
// cnt[qt*N+d] ends as per-quartile in-degree; atomic return value is the slot.
// csr2[(qt*CAP_Q+slot)*N + d] = src*10 (pre-scaled float4 index), slot-major
// so hop index loads coalesce across consecutive d.
__global__ __launch_bounds__(256) void build_kernel(
    const int* __restrict__ src, const int* __restrict__ dst,
    int* __restrict__ deg_out, int* __restrict__ cnt, int* __restrict__ csr2)
{
    int e = blockIdx.x * 256 + threadIdx.x;
    if (e < N_EDGES) {
        int s = src[e], d = dst[e];
        atomicAdd(&deg_out[s], 1);
        int qt = s / QNODES;
        int off = atomicAdd(&cnt[qt * N_NODES + d], 1);
        if (off < CAP_Q) csr2[(size_t)(qt * CAP_Q + off) * N_NODES + d] = s * 10;
    }
}

__global__ __launch_bounds__(256) void inv_kernel(
    const int* __restrict__ deg_out, const int* __restrict__ cnt,
    float* __restrict__ inv_out, float* __restrict__ inv_in)
{
    int i = blockIdx.x * 256 + threadIdx.x;
    if (i < N_NODES) {
        int a = deg_out[i];
        int b = cnt[i] + cnt[N_NODES + i] + cnt[2 * N_NODES + i] + cnt[3 * N_NODES + i];
        inv_out[i] = (a > 0) ? rsqrtf((float)a) : 0.f;
        inv_in[i]  = (b > 0) ? rsqrtf((float)b) : 0.f;
    }
}

// ---------------- one APPNP hop pass ----------------
// pass p gathers only src in [p*25K, (p+1)*25K) -> u-slice of exactly 4 MB,
// resident in each XCD's L2 after compulsory fill. Partial sums stream through
// `part` (nontemporal RMW, coalesced). pass 3 finalizes: res = h0 + 0.9*inv_in*acc,
// then writes u_next = inv_out*res (or raw res on the last hop).
__global__ __launch_bounds__(256) void hop_pass_kernel(
    const floatx4* __restrict__ ucur, const floatx4* __restrict__ h0,
    const int* __restrict__ cnt, const int* __restrict__ csr2,
    const float* __restrict__ inv_in, const float* __restrict__ inv_out,
    floatx4* __restrict__ part, int pass, int last)
{
    int gid = blockIdx.x * 256 + threadIdx.x;
    if (gid >= 10 * N_NODES) return;
    int d = gid / 10;
    int q = gid - d * 10;

    const int* col = csr2 + (size_t)pass * CAP_Q * N_NODES + d;
    int len = __builtin_nontemporal_load(cnt + pass * N_NODES + d);
    if (len > CAP_Q) len = CAP_Q;

    floatx4 acc;
    if (pass == 0) acc = (floatx4){0.f, 0.f, 0.f, 0.f};
    else           acc = __builtin_nontemporal_load(part + gid);

    int j = 0;
    for (; j + 4 <= len; j += 4) {
        int s0 = __builtin_nontemporal_load(col + (size_t)(j + 0) * N_NODES);
        int s1 = __builtin_nontemporal_load(col + (size_t)(j + 1) * N_NODES);
        int s2 = __builtin_nontemporal_load(col + (size_t)(j + 2) * N_NODES);
        int s3 = __builtin_nontemporal_load(col + (size_t)(j + 3) * N_NODES);
        floatx4 v0 = ucur[s0 + q];
        floatx4 v1 = ucur[s1 + q];
        floatx4 v2 = ucur[s2 + q];
        floatx4 v3 = ucur[s3 + q];
        acc += (v0 + v1) + (v2 + v3);
    }
    for (; j < len; ++j) {
        int s = __builtin_nontemporal_load(col + (size_t)j * N_NODES);
        acc += ucur[s + q];
    }

    if (pass < NPASS - 1) {
        __builtin_nontemporal_store(acc, part + gid);
    } else {
        floatx4 h0v = __builtin_nontemporal_load(h0 + gid);   // pre-scaled 0.1*h0
        float wi = 0.9f * inv_in[d];
        floatx4 res = h0v + wi * acc;
        if (!last) res = inv_out[d] * res;
        __builtin_nontemporal_store(res, part + gid);
    }
}

extern "C" void kernel_launch(void* const* d_in, const int* in_sizes, int n_in,
                              void* d_out, int out_size, void* d_ws, size_t ws_size,
                              hipStream_t stream) {
    const float* x  = (const float*)d_in[0];
    const int*   ei = (const int*)d_in[1];
    const int*   src = ei;
    const int*   dst = ei + N_EDGES;
    const float* Wb = (const float*)d_in[2];
    const float* bb = (const float*)d_in[3];
    const float* W1 = (const float*)d_in[4];
    const float* b1 = (const float*)d_in[5];
    const float* W2 = (const float*)d_in[6];
    const float* b2 = (const float*)d_in[7];

    float* out_adj    = (float*)d_out;            // doubles as u ping buffer "O"
    float* out_scores = (float*)d_out + 4000000;

    float* h0      = (float*)d_ws;                      // 4,000,000 f (0.1*h0, node-major)
    float* uA      = h0 + 4000000;                      // 4,000,000 f (u ping "A")
    int* deg_out   = (int*)(uA + 4000000);              // N
    int* cnt       = deg_out + N_NODES;                 // 4*N (per-quartile in-degree)
    float* inv_o   = (float*)(cnt + 4 * N_NODES);       // N
    float* inv_i   = inv_o + N_NODES;                   // N
    int* csr2      = (int*)(inv_i + N_NODES);           // 4*CAP_Q*N ints
    short* WT      = (short*)(csr2 + (size_t)NPASS * CAP_Q * N_NODES);
    short* W1T     = WT + 48 * 512;
    short* W2T     = W1T + 64 * 64;

    hipMemsetAsync(deg_out, 0, 5 * N_NODES * sizeof(int), stream);

    build_kernel<<<N_EDGES / 256, 256, 0, stream>>>(src, dst, deg_out, cnt, csr2);
    inv_kernel<<<NB1, 256, 0, stream>>>(deg_out, cnt, inv_o, inv_i);

    wt_kernel<<<96, 256, 0, stream>>>(Wb, W1, W2, WT, W1T, W2T);
    scores_kernel<<<1563, 256, 0, stream>>>(
        x, (const short8*)WT, bb, out_scores);
    // u0 -> out_adj region ("O"); h0 -> ws
    mlp_kernel<<<1250, 320, 0, stream>>>(
        out_scores, (const short8*)W1T, b1, (const short8*)W2T, b2,
        h0, out_adj, inv_o);

    // Ping-pong: even k reads O writes A, odd k reads A writes O.
    // k=9 (odd) reads A, finalizes into out_adj.
    int nblk = (10 * N_NODES + 255) / 256;
    for (int k = 0; k < 10; ++k) {
        const float* cur = (k & 1) ? uA : out_adj;
        float* nxt       = (k & 1) ? out_adj : uA;
        int last = (k == 9);
        for (int p = 0; p < NPASS; ++p) {
            hop_pass_kernel<<<nblk, 256, 0, stream>>>(
                (const floatx4*)cur, (const floatx4*)h0, cnt, csr2,
                inv_i, inv_o, (floatx4*)nxt, p, last);
        }
    }
}

// Round 5
// 932.564 us; speedup vs baseline: 1.3617x; 1.3617x over previous
//
#include <hip/hip_runtime.h>

#define N_NODES 100000
#define N_EDGES 1600000
#define QNODES 25000      // nodes per src-quartile; u-slice = 25000*160B = 4 MB = per-XCD L2
#define NPASS 4
#define CAP_Q 24          // slots per (node, quartile); P(Poisson(4) >= 24) ~ 1e-11
#define NB1 391           // ceil(N_NODES/256)

typedef __attribute__((ext_vector_type(8))) short short8;
typedef __attribute__((ext_vector_type(4))) float floatx4;

__device__ inline short bf16_rne(float f) {
    union { float f; unsigned u; } v; v.f = f;
    unsigned r = v.u + 0x7FFF + ((v.u >> 16) & 1);
    return (short)(r >> 16);
}

// ---------------- weight prep: all transposed, bf16, zero-padded ----------------
__global__ __launch_bounds__(256) void wt_kernel(
    const float* __restrict__ Wb, const float* __restrict__ W1,
    const float* __restrict__ W2,
    short* __restrict__ WT, short* __restrict__ W1T, short* __restrict__ W2T)
{
    int i = blockIdx.x * 256 + threadIdx.x;
    if (i < 48 * 512) {
        int m = i >> 9, k = i & 511;
        WT[i] = bf16_rne((m < 40 && k < 500) ? Wb[k * 40 + m] : 0.f);
    }
    if (i < 64 * 64) {
        int m = i >> 6, k = i & 63;
        W1T[i] = bf16_rne((k < 40) ? W1[k * 64 + m] : 0.f);
    }
    if (i < 48 * 64) {
        int m = i >> 6, k = i & 63;
        W2T[i] = bf16_rne((m < 40) ? W2[k * 40 + m] : 0.f);
    }
}

// ---------------- scores = x @ W_base + b_base via MFMA ----------------
__global__ __launch_bounds__(256) void scores_kernel(
    const float* __restrict__ x, const short8* __restrict__ WT8,
    const float* __restrict__ bb, float* __restrict__ scores)
{
    int wave = threadIdx.x >> 6;
    int lane = threadIdx.x & 63;
    int n0 = (blockIdx.x * 4 + wave) * 16;
    if (n0 >= N_NODES) return;
    int n = n0 + (lane & 15);
    int quad = lane >> 4;
    int m = lane & 15;
    const float* xrow = x + (size_t)n * 500 + quad * 8;

    floatx4 acc0 = {0,0,0,0}, acc1 = {0,0,0,0}, acc2 = {0,0,0,0};

    #pragma unroll 5
    for (int ks = 0; ks < 15; ++ks) {
        int k0 = ks * 32;
        float4 xa = *(const float4*)(xrow + k0);
        float4 xb = *(const float4*)(xrow + k0 + 4);
        short8 bf;
        bf[0] = bf16_rne(xa.x); bf[1] = bf16_rne(xa.y);
        bf[2] = bf16_rne(xa.z); bf[3] = bf16_rne(xa.w);
        bf[4] = bf16_rne(xb.x); bf[5] = bf16_rne(xb.y);
        bf[6] = bf16_rne(xb.z); bf[7] = bf16_rne(xb.w);
        int widx = (k0 >> 3) + quad;
        short8 a0 = WT8[(size_t)(0  + m) * 64 + widx];
        short8 a1 = WT8[(size_t)(16 + m) * 64 + widx];
        short8 a2 = WT8[(size_t)(32 + m) * 64 + widx];
        acc0 = __builtin_amdgcn_mfma_f32_16x16x32_bf16(a0, bf, acc0, 0, 0, 0);
        acc1 = __builtin_amdgcn_mfma_f32_16x16x32_bf16(a1, bf, acc1, 0, 0, 0);
        acc2 = __builtin_amdgcn_mfma_f32_16x16x32_bf16(a2, bf, acc2, 0, 0, 0);
    }
    {   // K tail
        int kbase = 480 + quad * 8;
        float4 xa = {0,0,0,0}, xb = {0,0,0,0};
        if (kbase + 8 <= 500) { xa = *(const float4*)(xrow + 480); xb = *(const float4*)(xrow + 484); }
        else if (kbase < 500) { xa = *(const float4*)(xrow + 480); }
        short8 bf;
        bf[0] = bf16_rne(xa.x); bf[1] = bf16_rne(xa.y);
        bf[2] = bf16_rne(xa.z); bf[3] = bf16_rne(xa.w);
        bf[4] = bf16_rne(xb.x); bf[5] = bf16_rne(xb.y);
        bf[6] = bf16_rne(xb.z); bf[7] = bf16_rne(xb.w);
        int widx = 60 + quad;
        short8 a0 = WT8[(size_t)(0  + m) * 64 + widx];
        short8 a1 = WT8[(size_t)(16 + m) * 64 + widx];
        short8 a2 = WT8[(size_t)(32 + m) * 64 + widx];
        acc0 = __builtin_amdgcn_mfma_f32_16x16x32_bf16(a0, bf, acc0, 0, 0, 0);
        acc1 = __builtin_amdgcn_mfma_f32_16x16x32_bf16(a1, bf, acc1, 0, 0, 0);
        acc2 = __builtin_amdgcn_mfma_f32_16x16x32_bf16(a2, bf, acc2, 0, 0, 0);
    }

    float* srow = scores + (size_t)n * 40;
    int mb = quad * 4;
    float4 b4 = *(const float4*)(bb + mb);
    *(float4*)(srow + mb) = make_float4(acc0[0] + b4.x, acc0[1] + b4.y,
                                        acc0[2] + b4.z, acc0[3] + b4.w);
    mb = 16 + quad * 4;
    b4 = *(const float4*)(bb + mb);
    *(float4*)(srow + mb) = make_float4(acc1[0] + b4.x, acc1[1] + b4.y,
                                        acc1[2] + b4.z, acc1[3] + b4.w);
    mb = 32 + quad * 4;
    if (mb < 40) {
        b4 = *(const float4*)(bb + mb);
        *(float4*)(srow + mb) = make_float4(acc2[0] + b4.x, acc2[1] + b4.y,
                                            acc2[2] + b4.z, acc2[3] + b4.w);
    }
}

// ---------------- fused softmax + MLP via MFMA ----------------
// Node-major outputs: h0[node][40] = 0.1*h (alpha pre-folded),
//                     u0[node][40] = inv_out[node]*h (propagation state)
__global__ __launch_bounds__(320) void mlp_kernel(
    const float* __restrict__ scores,
    const short8* __restrict__ W1T8, const float* __restrict__ b1,
    const short8* __restrict__ W2T8, const float* __restrict__ b2,
    float* __restrict__ h0, float* __restrict__ u0,
    const float* __restrict__ inv_out)
{
    __shared__ short hs[5][16 * 72];
    int wave = threadIdx.x >> 6;
    int lane = threadIdx.x & 63;
    int q = lane >> 4;
    int n16 = lane & 15;
    int node = (blockIdx.x * 5 + wave) * 16 + n16;
    float iv = inv_out[node];

    const float* srow = scores + (size_t)node * 40;
    float4 xa = *(const float4*)(srow + q * 8);
    float4 xb = *(const float4*)(srow + q * 8 + 4);
    float4 xc = {0,0,0,0}, xd = {0,0,0,0};
    if (q == 0) { xc = *(const float4*)(srow + 32); xd = *(const float4*)(srow + 36); }

    float m = fmaxf(fmaxf(fmaxf(xa.x, xa.y), fmaxf(xa.z, xa.w)),
                    fmaxf(fmaxf(xb.x, xb.y), fmaxf(xb.z, xb.w)));
    if (q == 0)
        m = fmaxf(m, fmaxf(fmaxf(fmaxf(xc.x, xc.y), fmaxf(xc.z, xc.w)),
                           fmaxf(fmaxf(xd.x, xd.y), fmaxf(xd.z, xd.w))));
    m = fmaxf(m, __shfl_xor(m, 16));
    m = fmaxf(m, __shfl_xor(m, 32));

    float e0 = __expf(xa.x - m), e1 = __expf(xa.y - m), e2 = __expf(xa.z - m), e3 = __expf(xa.w - m);
    float e4 = __expf(xb.x - m), e5 = __expf(xb.y - m), e6 = __expf(xb.z - m), e7 = __expf(xb.w - m);
    float f0 = 0, f1 = 0, f2 = 0, f3 = 0, f4 = 0, f5 = 0, f6 = 0, f7 = 0;
    if (q == 0) {
        f0 = __expf(xc.x - m); f1 = __expf(xc.y - m); f2 = __expf(xc.z - m); f3 = __expf(xc.w - m);
        f4 = __expf(xd.x - m); f5 = __expf(xd.y - m); f6 = __expf(xd.z - m); f7 = __expf(xd.w - m);
    }
    float sum = e0 + e1 + e2 + e3 + e4 + e5 + e6 + e7 + f0 + f1 + f2 + f3 + f4 + f5 + f6 + f7;
    sum += __shfl_xor(sum, 16);
    sum += __shfl_xor(sum, 32);
    float inv = 1.f / sum;

    short8 bf_a, bf_b;
    bf_a[0] = bf16_rne(e0 * inv); bf_a[1] = bf16_rne(e1 * inv);
    bf_a[2] = bf16_rne(e2 * inv); bf_a[3] = bf16_rne(e3 * inv);
    bf_a[4] = bf16_rne(e4 * inv); bf_a[5] = bf16_rne(e5 * inv);
    bf_a[6] = bf16_rne(e6 * inv); bf_a[7] = bf16_rne(e7 * inv);
    bf_b[0] = bf16_rne(f0 * inv); bf_b[1] = bf16_rne(f1 * inv);
    bf_b[2] = bf16_rne(f2 * inv); bf_b[3] = bf16_rne(f3 * inv);
    bf_b[4] = bf16_rne(f4 * inv); bf_b[5] = bf16_rne(f5 * inv);
    bf_b[6] = bf16_rne(f6 * inv); bf_b[7] = bf16_rne(f7 * inv);

    short* hw = &hs[wave][0];
    #pragma unroll
    for (int t = 0; t < 4; ++t) {
        floatx4 acc = {0, 0, 0, 0};
        short8 A0 = W1T8[(t * 16 + n16) * 8 + q];
        short8 A1 = W1T8[(t * 16 + n16) * 8 + 4 + q];
        acc = __builtin_amdgcn_mfma_f32_16x16x32_bf16(A0, bf_a, acc, 0, 0, 0);
        acc = __builtin_amdgcn_mfma_f32_16x16x32_bf16(A1, bf_b, acc, 0, 0, 0);
        float4 bv = *(const float4*)(b1 + t * 16 + q * 4);
        short4 pk;
        pk.x = bf16_rne(fmaxf(acc[0] + bv.x, 0.f));
        pk.y = bf16_rne(fmaxf(acc[1] + bv.y, 0.f));
        pk.z = bf16_rne(fmaxf(acc[2] + bv.z, 0.f));
        pk.w = bf16_rne(fmaxf(acc[3] + bv.w, 0.f));
        *(short4*)(hw + n16 * 72 + t * 16 + q * 4) = pk;
    }
    __syncthreads();

    short8 h1a = *(const short8*)(hw + n16 * 72 + q * 8);
    short8 h1b = *(const short8*)(hw + n16 * 72 + 32 + q * 8);

    #pragma unroll
    for (int t = 0; t < 3; ++t) {
        floatx4 acc = {0, 0, 0, 0};
        short8 A0 = W2T8[(t * 16 + n16) * 8 + q];
        short8 A1 = W2T8[(t * 16 + n16) * 8 + 4 + q];
        acc = __builtin_amdgcn_mfma_f32_16x16x32_bf16(A0, h1a, acc, 0, 0, 0);
        acc = __builtin_amdgcn_mfma_f32_16x16x32_bf16(A1, h1b, acc, 0, 0, 0);
        int mc = t * 16 + q * 4;
        if (mc < 40) {
            float4 bv = *(const float4*)(b2 + mc);
            float rx = acc[0] + bv.x, ry = acc[1] + bv.y;
            float rz = acc[2] + bv.z, rw = acc[3] + bv.w;
            size_t idx = (size_t)node * 10 + t * 4 + q;   // node-major float4 slot
            ((float4*)h0)[idx] = make_float4(0.1f * rx, 0.1f * ry, 0.1f * rz, 0.1f * rw);
            ((float4*)u0)[idx] = make_float4(iv * rx, iv * ry, iv * rz, iv * rw);
        }
    }
}

// ---------------- fused degree count + quartile-bucketed CSR (no scan) ----------------
// cnt[qt*N+d] ends as per-quartile in-degree; atomic return value is the slot.
// csr2[(qt*CAP_Q+slot)*N + d] = src*10 (pre-scaled float4 index), slot-major
// so hop index loads coalesce across consecutive d.
__global__ __launch_bounds__(256) void build_kernel(
    const int* __restrict__ src, const int* __restrict__ dst,
    int* __restrict__ deg_out, int* __restrict__ cnt, int* __restrict__ csr2)
{
    int e = blockIdx.x * 256 + threadIdx.x;
    if (e < N_EDGES) {
        int s = src[e], d = dst[e];
        atomicAdd(&deg_out[s], 1);
        int qt = s / QNODES;
        int off = atomicAdd(&cnt[qt * N_NODES + d], 1);
        if (off < CAP_Q) csr2[(size_t)(qt * CAP_Q + off) * N_NODES + d] = s * 10;
    }
}

__global__ __launch_bounds__(256) void inv_kernel(
    const int* __restrict__ deg_out, const int* __restrict__ cnt,
    float* __restrict__ inv_out, float* __restrict__ inv_in)
{
    int i = blockIdx.x * 256 + threadIdx.x;
    if (i < N_NODES) {
        int a = deg_out[i];
        int b = cnt[i] + cnt[N_NODES + i] + cnt[2 * N_NODES + i] + cnt[3 * N_NODES + i];
        inv_out[i] = (a > 0) ? rsqrtf((float)a) : 0.f;
        inv_in[i]  = (b > 0) ? rsqrtf((float)b) : 0.f;
    }
}

// ---------------- one APPNP hop, quartile-ordered, register accumulation ----------------
// Thread = (node d, quad q), gid = d*10+q (proven Round-2 mapping: broadcast index
// loads, 160B-contiguous gathers). Neighbor list is walked in src-quartile order;
// since ~2000 blocks are co-resident and advance in rough lockstep, concurrent
// gathers concentrate on one ~4MB u-slice at a time (fits per-XCD L2).
// Accumulator stays in registers across quartiles: zero extra memory traffic.
__global__ __launch_bounds__(256) void hop_kernel(
    const float4* __restrict__ ucur, const float4* __restrict__ h0,
    const int* __restrict__ cnt, const int* __restrict__ csr2,
    const float* __restrict__ inv_in, const float* __restrict__ inv_out,
    float4* __restrict__ unew, int last)
{
    int gid = blockIdx.x * 256 + threadIdx.x;
    if (gid >= 10 * N_NODES) return;
    int d = gid / 10;
    int q = gid - d * 10;

    float4 acc = make_float4(0.f, 0.f, 0.f, 0.f);

    #pragma unroll
    for (int p = 0; p < NPASS; ++p) {
        const int* col = csr2 + (size_t)p * CAP_Q * N_NODES + d;
        int len = cnt[p * N_NODES + d];
        if (len > CAP_Q) len = CAP_Q;
        int j = 0;
        for (; j + 4 <= len; j += 4) {
            int s0 = col[(size_t)(j + 0) * N_NODES];
            int s1 = col[(size_t)(j + 1) * N_NODES];
            int s2 = col[(size_t)(j + 2) * N_NODES];
            int s3 = col[(size_t)(j + 3) * N_NODES];
            float4 v0 = ucur[s0 + q];
            float4 v1 = ucur[s1 + q];
            float4 v2 = ucur[s2 + q];
            float4 v3 = ucur[s3 + q];
            acc.x += (v0.x + v1.x) + (v2.x + v3.x);
            acc.y += (v0.y + v1.y) + (v2.y + v3.y);
            acc.z += (v0.z + v1.z) + (v2.z + v3.z);
            acc.w += (v0.w + v1.w) + (v2.w + v3.w);
        }
        for (; j < len; ++j) {
            int s = col[(size_t)j * N_NODES];
            float4 v = ucur[s + q];
            acc.x += v.x; acc.y += v.y; acc.z += v.z; acc.w += v.w;
        }
    }

    float4 h0v = h0[gid];                 // pre-scaled 0.1*h0
    float wi = 0.9f * inv_in[d];
    float4 res = make_float4(h0v.x + wi * acc.x, h0v.y + wi * acc.y,
                             h0v.z + wi * acc.z, h0v.w + wi * acc.w);
    if (!last) {
        float io = inv_out[d];
        res = make_float4(io * res.x, io * res.y, io * res.z, io * res.w);
    }
    unew[gid] = res;
}

extern "C" void kernel_launch(void* const* d_in, const int* in_sizes, int n_in,
                              void* d_out, int out_size, void* d_ws, size_t ws_size,
                              hipStream_t stream) {
    const float* x  = (const float*)d_in[0];
    const int*   ei = (const int*)d_in[1];
    const int*   src = ei;
    const int*   dst = ei + N_EDGES;
    const float* Wb = (const float*)d_in[2];
    const float* bb = (const float*)d_in[3];
    const float* W1 = (const float*)d_in[4];
    const float* b1 = (const float*)d_in[5];
    const float* W2 = (const float*)d_in[6];
    const float* b2 = (const float*)d_in[7];

    float* out_adj    = (float*)d_out;            // doubles as u ping buffer "O"
    float* out_scores = (float*)d_out + 4000000;

    float* h0      = (float*)d_ws;                      // 4,000,000 f (0.1*h0, node-major)
    float* uA      = h0 + 4000000;                      // 4,000,000 f (u ping "A")
    int* deg_out   = (int*)(uA + 4000000);              // N
    int* cnt       = deg_out + N_NODES;                 // 4*N (per-quartile in-degree)
    float* inv_o   = (float*)(cnt + 4 * N_NODES);       // N
    float* inv_i   = inv_o + N_NODES;                   // N
    int* csr2      = (int*)(inv_i + N_NODES);           // 4*CAP_Q*N ints
    short* WT      = (short*)(csr2 + (size_t)NPASS * CAP_Q * N_NODES);
    short* W1T     = WT + 48 * 512;
    short* W2T     = W1T + 64 * 64;

    hipMemsetAsync(deg_out, 0, 5 * N_NODES * sizeof(int), stream);

    build_kernel<<<N_EDGES / 256, 256, 0, stream>>>(src, dst, deg_out, cnt, csr2);
    inv_kernel<<<NB1, 256, 0, stream>>>(deg_out, cnt, inv_o, inv_i);

    wt_kernel<<<96, 256, 0, stream>>>(Wb, W1, W2, WT, W1T, W2T);
    scores_kernel<<<1563, 256, 0, stream>>>(
        x, (const short8*)WT, bb, out_scores);
    // u0 -> out_adj region ("O"); h0 -> ws
    mlp_kernel<<<1250, 320, 0, stream>>>(
        out_scores, (const short8*)W1T, b1, (const short8*)W2T, b2,
        h0, out_adj, inv_o);

    // Ping-pong: even k reads O writes A, odd k reads A writes O.
    // k=9 (odd) reads A, finalizes into out_adj.
    int nblk = (10 * N_NODES + 255) / 256;
    for (int k = 0; k < 10; ++k) {
        const float* cur = (k & 1) ? uA : out_adj;
        float* nxt       = (k & 1) ? out_adj : uA;
        int last = (k == 9);
        hop_kernel<<<nblk, 256, 0, stream>>>(
            (const float4*)cur, (const float4*)h0, cnt, csr2,
            inv_i, inv_o, (float4*)nxt, last);
    }
}

// Round 6
// 830.191 us; speedup vs baseline: 1.5296x; 1.1233x over previous
//
#include <hip/hip_runtime.h>

#define N_NODES 100000
#define N_EDGES 1600000
#define QNODES 25000      // nodes per src-quartile; bf16 u-slice = 25000*80B = 2 MB << 4 MB L2
#define NPASS 4
#define CAP_Q 24          // slots per (node, quartile); P(Poisson(4) >= 24) ~ 1e-11
#define NB1 391           // ceil(N_NODES/256)
#define SCORES_BLKS 1563  // ceil(N_NODES/64) for 4 waves x 16 nodes
#define BUILD_BLKS 6250   // N_EDGES/256

typedef __attribute__((ext_vector_type(8))) short short8;
typedef __attribute__((ext_vector_type(4))) float floatx4;

__device__ inline short bf16_rne(float f) {
    union { float f; unsigned u; } v; v.f = f;
    unsigned r = v.u + 0x7FFF + ((v.u >> 16) & 1);
    return (short)(r >> 16);
}
__device__ inline float bf2f(unsigned short h) {
    union { unsigned u; float f; } v; v.u = (unsigned)h << 16;
    return v.f;
}

// ---------------- weight prep: all transposed, bf16, zero-padded ----------------
__global__ __launch_bounds__(256) void wt_kernel(
    const float* __restrict__ Wb, const float* __restrict__ W1,
    const float* __restrict__ W2,
    short* __restrict__ WT, short* __restrict__ W1T, short* __restrict__ W2T)
{
    int i = blockIdx.x * 256 + threadIdx.x;
    if (i < 48 * 512) {
        int m = i >> 9, k = i & 511;
        WT[i] = bf16_rne((m < 40 && k < 500) ? Wb[k * 40 + m] : 0.f);
    }
    if (i < 64 * 64) {
        int m = i >> 6, k = i & 63;
        W1T[i] = bf16_rne((k < 40) ? W1[k * 64 + m] : 0.f);
    }
    if (i < 48 * 64) {
        int m = i >> 6, k = i & 63;
        W2T[i] = bf16_rne((m < 40) ? W2[k * 40 + m] : 0.f);
    }
}

// ---------------- fused: scores (blocks [0,1563)) || CSR build (blocks [1563,7813)) ----
// Independent work, different bound resources (MFMA+stream vs atomic transactions):
// co-scheduling hides scores almost entirely under build.
__global__ __launch_bounds__(256) void mega_kernel(
    const float* __restrict__ x, const short8* __restrict__ WT8,
    const float* __restrict__ bb, float* __restrict__ scores,
    const int* __restrict__ src, const int* __restrict__ dst,
    int* __restrict__ deg_out, int* __restrict__ cnt, int* __restrict__ csr2)
{
    if (blockIdx.x >= SCORES_BLKS) {
        // ---- build path: degree count + quartile-bucketed slot-major CSR ----
        int e = (blockIdx.x - SCORES_BLKS) * 256 + threadIdx.x;
        if (e < N_EDGES) {
            int s = src[e], d = dst[e];
            atomicAdd(&deg_out[s], 1);
            int qt = s / QNODES;
            int off = atomicAdd(&cnt[qt * N_NODES + d], 1);
            if (off < CAP_Q) csr2[(size_t)(qt * CAP_Q + off) * N_NODES + d] = s * 10;
        }
        return;
    }

    // ---- scores path: scores = x @ W_base + b_base via MFMA ----
    int wave = threadIdx.x >> 6;
    int lane = threadIdx.x & 63;
    int n0 = (blockIdx.x * 4 + wave) * 16;
    if (n0 >= N_NODES) return;
    int n = n0 + (lane & 15);
    int quad = lane >> 4;
    int m = lane & 15;
    const float* xrow = x + (size_t)n * 500 + quad * 8;

    floatx4 acc0 = {0,0,0,0}, acc1 = {0,0,0,0}, acc2 = {0,0,0,0};

    #pragma unroll 5
    for (int ks = 0; ks < 15; ++ks) {
        int k0 = ks * 32;
        float4 xa = *(const float4*)(xrow + k0);
        float4 xb = *(const float4*)(xrow + k0 + 4);
        short8 bf;
        bf[0] = bf16_rne(xa.x); bf[1] = bf16_rne(xa.y);
        bf[2] = bf16_rne(xa.z); bf[3] = bf16_rne(xa.w);
        bf[4] = bf16_rne(xb.x); bf[5] = bf16_rne(xb.y);
        bf[6] = bf16_rne(xb.z); bf[7] = bf16_rne(xb.w);
        int widx = (k0 >> 3) + quad;
        short8 a0 = WT8[(size_t)(0  + m) * 64 + widx];
        short8 a1 = WT8[(size_t)(16 + m) * 64 + widx];
        short8 a2 = WT8[(size_t)(32 + m) * 64 + widx];
        acc0 = __builtin_amdgcn_mfma_f32_16x16x32_bf16(a0, bf, acc0, 0, 0, 0);
        acc1 = __builtin_amdgcn_mfma_f32_16x16x32_bf16(a1, bf, acc1, 0, 0, 0);
        acc2 = __builtin_amdgcn_mfma_f32_16x16x32_bf16(a2, bf, acc2, 0, 0, 0);
    }
    {   // K tail
        int kbase = 480 + quad * 8;
        float4 xa = {0,0,0,0}, xb = {0,0,0,0};
        if (kbase + 8 <= 500) { xa = *(const float4*)(xrow + 480); xb = *(const float4*)(xrow + 484); }
        else if (kbase < 500) { xa = *(const float4*)(xrow + 480); }
        short8 bf;
        bf[0] = bf16_rne(xa.x); bf[1] = bf16_rne(xa.y);
        bf[2] = bf16_rne(xa.z); bf[3] = bf16_rne(xa.w);
        bf[4] = bf16_rne(xb.x); bf[5] = bf16_rne(xb.y);
        bf[6] = bf16_rne(xb.z); bf[7] = bf16_rne(xb.w);
        int widx = 60 + quad;
        short8 a0 = WT8[(size_t)(0  + m) * 64 + widx];
        short8 a1 = WT8[(size_t)(16 + m) * 64 + widx];
        short8 a2 = WT8[(size_t)(32 + m) * 64 + widx];
        acc0 = __builtin_amdgcn_mfma_f32_16x16x32_bf16(a0, bf, acc0, 0, 0, 0);
        acc1 = __builtin_amdgcn_mfma_f32_16x16x32_bf16(a1, bf, acc1, 0, 0, 0);
        acc2 = __builtin_amdgcn_mfma_f32_16x16x32_bf16(a2, bf, acc2, 0, 0, 0);
    }

    float* srow = scores + (size_t)n * 40;
    int mb = quad * 4;
    float4 b4 = *(const float4*)(bb + mb);
    *(float4*)(srow + mb) = make_float4(acc0[0] + b4.x, acc0[1] + b4.y,
                                        acc0[2] + b4.z, acc0[3] + b4.w);
    mb = 16 + quad * 4;
    b4 = *(const float4*)(bb + mb);
    *(float4*)(srow + mb) = make_float4(acc1[0] + b4.x, acc1[1] + b4.y,
                                        acc1[2] + b4.z, acc1[3] + b4.w);
    mb = 32 + quad * 4;
    if (mb < 40) {
        b4 = *(const float4*)(bb + mb);
        *(float4*)(srow + mb) = make_float4(acc2[0] + b4.x, acc2[1] + b4.y,
                                            acc2[2] + b4.z, acc2[3] + b4.w);
    }
}

__global__ __launch_bounds__(256) void inv_kernel(
    const int* __restrict__ deg_out, const int* __restrict__ cnt,
    float* __restrict__ inv_out, float* __restrict__ inv_in)
{
    int i = blockIdx.x * 256 + threadIdx.x;
    if (i < N_NODES) {
        int a = deg_out[i];
        int b = cnt[i] + cnt[N_NODES + i] + cnt[2 * N_NODES + i] + cnt[3 * N_NODES + i];
        inv_out[i] = (a > 0) ? rsqrtf((float)a) : 0.f;
        inv_in[i]  = (b > 0) ? rsqrtf((float)b) : 0.f;
    }
}

// ---------------- fused softmax + MLP via MFMA ----------------
// h0[node][40] f32 = 0.1*h (alpha pre-folded)
// u0[node][40] bf16 = inv_out[node]*h (propagation state, packed ushort4 per quad)
__global__ __launch_bounds__(320) void mlp_kernel(
    const float* __restrict__ scores,
    const short8* __restrict__ W1T8, const float* __restrict__ b1,
    const short8* __restrict__ W2T8, const float* __restrict__ b2,
    float* __restrict__ h0, ushort4* __restrict__ u0,
    const float* __restrict__ inv_out)
{
    __shared__ short hs[5][16 * 72];
    int wave = threadIdx.x >> 6;
    int lane = threadIdx.x & 63;
    int q = lane >> 4;
    int n16 = lane & 15;
    int node = (blockIdx.x * 5 + wave) * 16 + n16;
    float iv = inv_out[node];

    const float* srow = scores + (size_t)node * 40;
    float4 xa = *(const float4*)(srow + q * 8);
    float4 xb = *(const float4*)(srow + q * 8 + 4);
    float4 xc = {0,0,0,0}, xd = {0,0,0,0};
    if (q == 0) { xc = *(const float4*)(srow + 32); xd = *(const float4*)(srow + 36); }

    float m = fmaxf(fmaxf(fmaxf(xa.x, xa.y), fmaxf(xa.z, xa.w)),
                    fmaxf(fmaxf(xb.x, xb.y), fmaxf(xb.z, xb.w)));
    if (q == 0)
        m = fmaxf(m, fmaxf(fmaxf(fmaxf(xc.x, xc.y), fmaxf(xc.z, xc.w)),
                           fmaxf(fmaxf(xd.x, xd.y), fmaxf(xd.z, xd.w))));
    m = fmaxf(m, __shfl_xor(m, 16));
    m = fmaxf(m, __shfl_xor(m, 32));

    float e0 = __expf(xa.x - m), e1 = __expf(xa.y - m), e2 = __expf(xa.z - m), e3 = __expf(xa.w - m);
    float e4 = __expf(xb.x - m), e5 = __expf(xb.y - m), e6 = __expf(xb.z - m), e7 = __expf(xb.w - m);
    float f0 = 0, f1 = 0, f2 = 0, f3 = 0, f4 = 0, f5 = 0, f6 = 0, f7 = 0;
    if (q == 0) {
        f0 = __expf(xc.x - m); f1 = __expf(xc.y - m); f2 = __expf(xc.z - m); f3 = __expf(xc.w - m);
        f4 = __expf(xd.x - m); f5 = __expf(xd.y - m); f6 = __expf(xd.z - m); f7 = __expf(xd.w - m);
    }
    float sum = e0 + e1 + e2 + e3 + e4 + e5 + e6 + e7 + f0 + f1 + f2 + f3 + f4 + f5 + f6 + f7;
    sum += __shfl_xor(sum, 16);
    sum += __shfl_xor(sum, 32);
    float inv = 1.f / sum;

    short8 bf_a, bf_b;
    bf_a[0] = bf16_rne(e0 * inv); bf_a[1] = bf16_rne(e1 * inv);
    bf_a[2] = bf16_rne(e2 * inv); bf_a[3] = bf16_rne(e3 * inv);
    bf_a[4] = bf16_rne(e4 * inv); bf_a[5] = bf16_rne(e5 * inv);
    bf_a[6] = bf16_rne(e6 * inv); bf_a[7] = bf16_rne(e7 * inv);
    bf_b[0] = bf16_rne(f0 * inv); bf_b[1] = bf16_rne(f1 * inv);
    bf_b[2] = bf16_rne(f2 * inv); bf_b[3] = bf16_rne(f3 * inv);
    bf_b[4] = bf16_rne(f4 * inv); bf_b[5] = bf16_rne(f5 * inv);
    bf_b[6] = bf16_rne(f6 * inv); bf_b[7] = bf16_rne(f7 * inv);

    short* hw = &hs[wave][0];
    #pragma unroll
    for (int t = 0; t < 4; ++t) {
        floatx4 acc = {0, 0, 0, 0};
        short8 A0 = W1T8[(t * 16 + n16) * 8 + q];
        short8 A1 = W1T8[(t * 16 + n16) * 8 + 4 + q];
        acc = __builtin_amdgcn_mfma_f32_16x16x32_bf16(A0, bf_a, acc, 0, 0, 0);
        acc = __builtin_amdgcn_mfma_f32_16x16x32_bf16(A1, bf_b, acc, 0, 0, 0);
        float4 bv = *(const float4*)(b1 + t * 16 + q * 4);
        short4 pk;
        pk.x = bf16_rne(fmaxf(acc[0] + bv.x, 0.f));
        pk.y = bf16_rne(fmaxf(acc[1] + bv.y, 0.f));
        pk.z = bf16_rne(fmaxf(acc[2] + bv.z, 0.f));
        pk.w = bf16_rne(fmaxf(acc[3] + bv.w, 0.f));
        *(short4*)(hw + n16 * 72 + t * 16 + q * 4) = pk;
    }
    __syncthreads();

    short8 h1a = *(const short8*)(hw + n16 * 72 + q * 8);
    short8 h1b = *(const short8*)(hw + n16 * 72 + 32 + q * 8);

    #pragma unroll
    for (int t = 0; t < 3; ++t) {
        floatx4 acc = {0, 0, 0, 0};
        short8 A0 = W2T8[(t * 16 + n16) * 8 + q];
        short8 A1 = W2T8[(t * 16 + n16) * 8 + 4 + q];
        acc = __builtin_amdgcn_mfma_f32_16x16x32_bf16(A0, h1a, acc, 0, 0, 0);
        acc = __builtin_amdgcn_mfma_f32_16x16x32_bf16(A1, h1b, acc, 0, 0, 0);
        int mc = t * 16 + q * 4;
        if (mc < 40) {
            float4 bv = *(const float4*)(b2 + mc);
            float rx = acc[0] + bv.x, ry = acc[1] + bv.y;
            float rz = acc[2] + bv.z, rw = acc[3] + bv.w;
            size_t idx = (size_t)node * 10 + t * 4 + q;   // node-major quad slot
            ((float4*)h0)[idx] = make_float4(0.1f * rx, 0.1f * ry, 0.1f * rz, 0.1f * rw);
            ushort4 pk;
            pk.x = (unsigned short)bf16_rne(iv * rx);
            pk.y = (unsigned short)bf16_rne(iv * ry);
            pk.z = (unsigned short)bf16_rne(iv * rz);
            pk.w = (unsigned short)bf16_rne(iv * rw);
            u0[idx] = pk;
        }
    }
}

// ---------------- one APPNP hop, bf16 u, quartile-ordered, register accumulation ----
// Thread = (node d, quad q), gid = d*10+q. Gathers are 80B contiguous per node
// (ushort4 = 8B per lane); index loads broadcast across the 10 q-lanes.
// Quartile walk order concentrates concurrent gathers on a 2 MB u-slice (L2-hot).
// f32 accumulate; bf16 restore only on the stored u (h0 alpha term stays f32).
__global__ __launch_bounds__(256) void hop_kernel(
    const ushort4* __restrict__ ucur, const float4* __restrict__ h0,
    const int* __restrict__ cnt, const int* __restrict__ csr2,
    const float* __restrict__ inv_in, const float* __restrict__ inv_out,
    ushort4* __restrict__ unew, float4* __restrict__ outf, int last)
{
    int gid = blockIdx.x * 256 + threadIdx.x;
    if (gid >= 10 * N_NODES) return;
    int d = gid / 10;
    int q = gid - d * 10;

    float4 acc = make_float4(0.f, 0.f, 0.f, 0.f);

    #pragma unroll
    for (int p = 0; p < NPASS; ++p) {
        const int* col = csr2 + (size_t)p * CAP_Q * N_NODES + d;
        int len = cnt[p * N_NODES + d];
        if (len > CAP_Q) len = CAP_Q;
        int j = 0;
        for (; j + 4 <= len; j += 4) {
            int s0 = col[(size_t)(j + 0) * N_NODES];
            int s1 = col[(size_t)(j + 1) * N_NODES];
            int s2 = col[(size_t)(j + 2) * N_NODES];
            int s3 = col[(size_t)(j + 3) * N_NODES];
            ushort4 v0 = ucur[s0 + q];
            ushort4 v1 = ucur[s1 + q];
            ushort4 v2 = ucur[s2 + q];
            ushort4 v3 = ucur[s3 + q];
            acc.x += (bf2f(v0.x) + bf2f(v1.x)) + (bf2f(v2.x) + bf2f(v3.x));
            acc.y += (bf2f(v0.y) + bf2f(v1.y)) + (bf2f(v2.y) + bf2f(v3.y));
            acc.z += (bf2f(v0.z) + bf2f(v1.z)) + (bf2f(v2.z) + bf2f(v3.z));
            acc.w += (bf2f(v0.w) + bf2f(v1.w)) + (bf2f(v2.w) + bf2f(v3.w));
        }
        for (; j < len; ++j) {
            int s = col[(size_t)j * N_NODES];
            ushort4 v = ucur[s + q];
            acc.x += bf2f(v.x); acc.y += bf2f(v.y);
            acc.z += bf2f(v.z); acc.w += bf2f(v.w);
        }
    }

    float4 h0v = h0[gid];                 // pre-scaled 0.1*h0, f32
    float wi = 0.9f * inv_in[d];
    float4 res = make_float4(h0v.x + wi * acc.x, h0v.y + wi * acc.y,
                             h0v.z + wi * acc.z, h0v.w + wi * acc.w);
    if (last) {
        outf[gid] = res;                  // final hop: f32, node-major
    } else {
        float io = inv_out[d];
        ushort4 pk;
        pk.x = (unsigned short)bf16_rne(io * res.x);
        pk.y = (unsigned short)bf16_rne(io * res.y);
        pk.z = (unsigned short)bf16_rne(io * res.z);
        pk.w = (unsigned short)bf16_rne(io * res.w);
        unew[gid] = pk;
    }
}

extern "C" void kernel_launch(void* const* d_in, const int* in_sizes, int n_in,
                              void* d_out, int out_size, void* d_ws, size_t ws_size,
                              hipStream_t stream) {
    const float* x  = (const float*)d_in[0];
    const int*   ei = (const int*)d_in[1];
    const int*   src = ei;
    const int*   dst = ei + N_EDGES;
    const float* Wb = (const float*)d_in[2];
    const float* bb = (const float*)d_in[3];
    const float* W1 = (const float*)d_in[4];
    const float* b1 = (const float*)d_in[5];
    const float* W2 = (const float*)d_in[6];
    const float* b2 = (const float*)d_in[7];

    float* out_adj    = (float*)d_out;
    float* out_scores = (float*)d_out + 4000000;

    float* h0      = (float*)d_ws;                      // 4,000,000 f (0.1*h0, f32)
    ushort* ubfA   = (ushort*)(h0 + 4000000);           // 4,000,000 bf16 (u ping A)
    ushort* ubfB   = ubfA + 4000000;                    // 4,000,000 bf16 (u ping B)
    int* deg_out   = (int*)(ubfB + 4000000);            // N
    int* cnt       = deg_out + N_NODES;                 // 4*N (per-quartile in-degree)
    float* inv_o   = (float*)(cnt + 4 * N_NODES);       // N
    float* inv_i   = inv_o + N_NODES;                   // N
    int* csr2      = (int*)(inv_i + N_NODES);           // 4*CAP_Q*N ints
    short* WT      = (short*)(csr2 + (size_t)NPASS * CAP_Q * N_NODES);
    short* W1T     = WT + 48 * 512;
    short* W2T     = W1T + 64 * 64;

    hipMemsetAsync(deg_out, 0, 5 * N_NODES * sizeof(int), stream);

    wt_kernel<<<96, 256, 0, stream>>>(Wb, W1, W2, WT, W1T, W2T);
    mega_kernel<<<SCORES_BLKS + BUILD_BLKS, 256, 0, stream>>>(
        x, (const short8*)WT, bb, out_scores,
        src, dst, deg_out, cnt, csr2);
    inv_kernel<<<NB1, 256, 0, stream>>>(deg_out, cnt, inv_o, inv_i);

    mlp_kernel<<<1250, 320, 0, stream>>>(
        out_scores, (const short8*)W1T, b1, (const short8*)W2T, b2,
        h0, (ushort4*)ubfA, inv_o);

    // Ping-pong: even k reads A writes B, odd k reads B writes A.
    // k=9 (odd) reads B, finalizes f32 into out_adj.
    int nblk = (10 * N_NODES + 255) / 256;
    for (int k = 0; k < 10; ++k) {
        const ushort4* cur = (const ushort4*)((k & 1) ? ubfB : ubfA);
        ushort4* nxt       = (ushort4*)((k & 1) ? ubfA : ubfB);
        int last = (k == 9);
        hop_kernel<<<nblk, 256, 0, stream>>>(
            cur, (const float4*)h0, cnt, csr2,
            inv_i, inv_o, nxt, (float4*)out_adj, last);
    }
}

// Round 7
// 809.745 us; speedup vs baseline: 1.5682x; 1.0253x over previous
//
#include <hip/hip_runtime.h>

#define N_NODES 100000
#define N_EDGES 1600000
#define QH 50000          // nodes per src-half; bf16 u-slice = 50000*80B = 4 MB = per-XCD L2
#define NPASS 2
#define CAP_H 32          // slots per (node, half); max Poisson(8) over 200K draws ~ 24
#define NB1 391           // ceil(N_NODES/256)
#define BUILD_BLKS 6250   // N_EDGES/256
#define SCORES_BLKS 1563  // ceil(N_NODES/64)

typedef __attribute__((ext_vector_type(8))) short short8;
typedef __attribute__((ext_vector_type(4))) float floatx4;

__device__ inline short bf16_rne(float f) {
    union { float f; unsigned u; } v; v.f = f;
    unsigned r = v.u + 0x7FFF + ((v.u >> 16) & 1);
    return (short)(r >> 16);
}
__device__ inline float bf2f(unsigned short h) {
    union { unsigned u; float f; } v; v.u = (unsigned)h << 16;
    return v.f;
}

// ---------------- weight prep: all transposed, bf16, zero-padded ----------------
__global__ __launch_bounds__(256) void wt_kernel(
    const float* __restrict__ Wb, const float* __restrict__ W1,
    const float* __restrict__ W2,
    short* __restrict__ WT, short* __restrict__ W1T, short* __restrict__ W2T)
{
    int i = blockIdx.x * 256 + threadIdx.x;
    if (i < 48 * 512) {
        int m = i >> 9, k = i & 511;
        WT[i] = bf16_rne((m < 40 && k < 500) ? Wb[k * 40 + m] : 0.f);
    }
    if (i < 64 * 64) {
        int m = i >> 6, k = i & 63;
        W1T[i] = bf16_rne((k < 40) ? W1[k * 64 + m] : 0.f);
    }
    if (i < 48 * 64) {
        int m = i >> 6, k = i & 63;
        W2T[i] = bf16_rne((m < 40) ? W2[k * 40 + m] : 0.f);
    }
}

// ---------------- fused: CSR build (blocks [0,6250)) || scores (blocks [6250,7813)) ----
// Build first: it's the long pole (atomic-fabric bound, ~31B/atomic); scores' MFMA
// blocks fill in around it. csr2h is ushort + L2-resident (12.8 MB = 1.6 MB/XCD),
// so scattered stores coalesce in L2 instead of thrashing dirty lines to HBM.
__global__ __launch_bounds__(256) void mega_kernel(
    const float* __restrict__ x, const short8* __restrict__ WT8,
    const float* __restrict__ bb, float* __restrict__ scores,
    const int* __restrict__ src, const int* __restrict__ dst,
    int* __restrict__ deg_out, int* __restrict__ cnt,
    unsigned short* __restrict__ csr2h)
{
    if (blockIdx.x < BUILD_BLKS) {
        int e = blockIdx.x * 256 + threadIdx.x;
        if (e < N_EDGES) {
            int s = src[e], d = dst[e];
            atomicAdd(&deg_out[s], 1);
            int h = (s >= QH) ? 1 : 0;
            int off = atomicAdd(&cnt[h * N_NODES + d], 1);
            if (off < CAP_H)
                csr2h[(size_t)(h * CAP_H + off) * N_NODES + d] =
                    (unsigned short)(s - h * QH);
        }
        return;
    }

    // ---- scores path: scores = x @ W_base + b_base via MFMA ----
    int bid = blockIdx.x - BUILD_BLKS;
    int wave = threadIdx.x >> 6;
    int lane = threadIdx.x & 63;
    int n0 = (bid * 4 + wave) * 16;
    if (n0 >= N_NODES) return;
    int n = n0 + (lane & 15);
    int quad = lane >> 4;
    int m = lane & 15;
    const float* xrow = x + (size_t)n * 500 + quad * 8;

    floatx4 acc0 = {0,0,0,0}, acc1 = {0,0,0,0}, acc2 = {0,0,0,0};

    #pragma unroll 5
    for (int ks = 0; ks < 15; ++ks) {
        int k0 = ks * 32;
        float4 xa = *(const float4*)(xrow + k0);
        float4 xb = *(const float4*)(xrow + k0 + 4);
        short8 bf;
        bf[0] = bf16_rne(xa.x); bf[1] = bf16_rne(xa.y);
        bf[2] = bf16_rne(xa.z); bf[3] = bf16_rne(xa.w);
        bf[4] = bf16_rne(xb.x); bf[5] = bf16_rne(xb.y);
        bf[6] = bf16_rne(xb.z); bf[7] = bf16_rne(xb.w);
        int widx = (k0 >> 3) + quad;
        short8 a0 = WT8[(size_t)(0  + m) * 64 + widx];
        short8 a1 = WT8[(size_t)(16 + m) * 64 + widx];
        short8 a2 = WT8[(size_t)(32 + m) * 64 + widx];
        acc0 = __builtin_amdgcn_mfma_f32_16x16x32_bf16(a0, bf, acc0, 0, 0, 0);
        acc1 = __builtin_amdgcn_mfma_f32_16x16x32_bf16(a1, bf, acc1, 0, 0, 0);
        acc2 = __builtin_amdgcn_mfma_f32_16x16x32_bf16(a2, bf, acc2, 0, 0, 0);
    }
    {   // K tail
        int kbase = 480 + quad * 8;
        float4 xa = {0,0,0,0}, xb = {0,0,0,0};
        if (kbase + 8 <= 500) { xa = *(const float4*)(xrow + 480); xb = *(const float4*)(xrow + 484); }
        else if (kbase < 500) { xa = *(const float4*)(xrow + 480); }
        short8 bf;
        bf[0] = bf16_rne(xa.x); bf[1] = bf16_rne(xa.y);
        bf[2] = bf16_rne(xa.z); bf[3] = bf16_rne(xa.w);
        bf[4] = bf16_rne(xb.x); bf[5] = bf16_rne(xb.y);
        bf[6] = bf16_rne(xb.z); bf[7] = bf16_rne(xb.w);
        int widx = 60 + quad;
        short8 a0 = WT8[(size_t)(0  + m) * 64 + widx];
        short8 a1 = WT8[(size_t)(16 + m) * 64 + widx];
        short8 a2 = WT8[(size_t)(32 + m) * 64 + widx];
        acc0 = __builtin_amdgcn_mfma_f32_16x16x32_bf16(a0, bf, acc0, 0, 0, 0);
        acc1 = __builtin_amdgcn_mfma_f32_16x16x32_bf16(a1, bf, acc1, 0, 0, 0);
        acc2 = __builtin_amdgcn_mfma_f32_16x16x32_bf16(a2, bf, acc2, 0, 0, 0);
    }

    float* srow = scores + (size_t)n * 40;
    int mb = quad * 4;
    float4 b4 = *(const float4*)(bb + mb);
    *(float4*)(srow + mb) = make_float4(acc0[0] + b4.x, acc0[1] + b4.y,
                                        acc0[2] + b4.z, acc0[3] + b4.w);
    mb = 16 + quad * 4;
    b4 = *(const float4*)(bb + mb);
    *(float4*)(srow + mb) = make_float4(acc1[0] + b4.x, acc1[1] + b4.y,
                                        acc1[2] + b4.z, acc1[3] + b4.w);
    mb = 32 + quad * 4;
    if (mb < 40) {
        b4 = *(const float4*)(bb + mb);
        *(float4*)(srow + mb) = make_float4(acc2[0] + b4.x, acc2[1] + b4.y,
                                            acc2[2] + b4.z, acc2[3] + b4.w);
    }
}

__global__ __launch_bounds__(256) void inv_kernel(
    const int* __restrict__ deg_out, const int* __restrict__ cnt,
    float* __restrict__ inv_out, float* __restrict__ inv_in)
{
    int i = blockIdx.x * 256 + threadIdx.x;
    if (i < N_NODES) {
        int a = deg_out[i];
        int b = cnt[i] + cnt[N_NODES + i];
        inv_out[i] = (a > 0) ? rsqrtf((float)a) : 0.f;
        inv_in[i]  = (b > 0) ? rsqrtf((float)b) : 0.f;
    }
}

// ---------------- fused softmax + MLP via MFMA ----------------
// h0[node][40] f32 = 0.1*h (alpha pre-folded)
// u0[node][40] bf16 = inv_out[node]*h (propagation state)
__global__ __launch_bounds__(320) void mlp_kernel(
    const float* __restrict__ scores,
    const short8* __restrict__ W1T8, const float* __restrict__ b1,
    const short8* __restrict__ W2T8, const float* __restrict__ b2,
    float* __restrict__ h0, ushort4* __restrict__ u0,
    const float* __restrict__ inv_out)
{
    __shared__ short hs[5][16 * 72];
    int wave = threadIdx.x >> 6;
    int lane = threadIdx.x & 63;
    int q = lane >> 4;
    int n16 = lane & 15;
    int node = (blockIdx.x * 5 + wave) * 16 + n16;
    float iv = inv_out[node];

    const float* srow = scores + (size_t)node * 40;
    float4 xa = *(const float4*)(srow + q * 8);
    float4 xb = *(const float4*)(srow + q * 8 + 4);
    float4 xc = {0,0,0,0}, xd = {0,0,0,0};
    if (q == 0) { xc = *(const float4*)(srow + 32); xd = *(const float4*)(srow + 36); }

    float m = fmaxf(fmaxf(fmaxf(xa.x, xa.y), fmaxf(xa.z, xa.w)),
                    fmaxf(fmaxf(xb.x, xb.y), fmaxf(xb.z, xb.w)));
    if (q == 0)
        m = fmaxf(m, fmaxf(fmaxf(fmaxf(xc.x, xc.y), fmaxf(xc.z, xc.w)),
                           fmaxf(fmaxf(xd.x, xd.y), fmaxf(xd.z, xd.w))));
    m = fmaxf(m, __shfl_xor(m, 16));
    m = fmaxf(m, __shfl_xor(m, 32));

    float e0 = __expf(xa.x - m), e1 = __expf(xa.y - m), e2 = __expf(xa.z - m), e3 = __expf(xa.w - m);
    float e4 = __expf(xb.x - m), e5 = __expf(xb.y - m), e6 = __expf(xb.z - m), e7 = __expf(xb.w - m);
    float f0 = 0, f1 = 0, f2 = 0, f3 = 0, f4 = 0, f5 = 0, f6 = 0, f7 = 0;
    if (q == 0) {
        f0 = __expf(xc.x - m); f1 = __expf(xc.y - m); f2 = __expf(xc.z - m); f3 = __expf(xc.w - m);
        f4 = __expf(xd.x - m); f5 = __expf(xd.y - m); f6 = __expf(xd.z - m); f7 = __expf(xd.w - m);
    }
    float sum = e0 + e1 + e2 + e3 + e4 + e5 + e6 + e7 + f0 + f1 + f2 + f3 + f4 + f5 + f6 + f7;
    sum += __shfl_xor(sum, 16);
    sum += __shfl_xor(sum, 32);
    float inv = 1.f / sum;

    short8 bf_a, bf_b;
    bf_a[0] = bf16_rne(e0 * inv); bf_a[1] = bf16_rne(e1 * inv);
    bf_a[2] = bf16_rne(e2 * inv); bf_a[3] = bf16_rne(e3 * inv);
    bf_a[4] = bf16_rne(e4 * inv); bf_a[5] = bf16_rne(e5 * inv);
    bf_a[6] = bf16_rne(e6 * inv); bf_a[7] = bf16_rne(e7 * inv);
    bf_b[0] = bf16_rne(f0 * inv); bf_b[1] = bf16_rne(f1 * inv);
    bf_b[2] = bf16_rne(f2 * inv); bf_b[3] = bf16_rne(f3 * inv);
    bf_b[4] = bf16_rne(f4 * inv); bf_b[5] = bf16_rne(f5 * inv);
    bf_b[6] = bf16_rne(f6 * inv); bf_b[7] = bf16_rne(f7 * inv);

    short* hw = &hs[wave][0];
    #pragma unroll
    for (int t = 0; t < 4; ++t) {
        floatx4 acc = {0, 0, 0, 0};
        short8 A0 = W1T8[(t * 16 + n16) * 8 + q];
        short8 A1 = W1T8[(t * 16 + n16) * 8 + 4 + q];
        acc = __builtin_amdgcn_mfma_f32_16x16x32_bf16(A0, bf_a, acc, 0, 0, 0);
        acc = __builtin_amdgcn_mfma_f32_16x16x32_bf16(A1, bf_b, acc, 0, 0, 0);
        float4 bv = *(const float4*)(b1 + t * 16 + q * 4);
        short4 pk;
        pk.x = bf16_rne(fmaxf(acc[0] + bv.x, 0.f));
        pk.y = bf16_rne(fmaxf(acc[1] + bv.y, 0.f));
        pk.z = bf16_rne(fmaxf(acc[2] + bv.z, 0.f));
        pk.w = bf16_rne(fmaxf(acc[3] + bv.w, 0.f));
        *(short4*)(hw + n16 * 72 + t * 16 + q * 4) = pk;
    }
    __syncthreads();

    short8 h1a = *(const short8*)(hw + n16 * 72 + q * 8);
    short8 h1b = *(const short8*)(hw + n16 * 72 + 32 + q * 8);

    #pragma unroll
    for (int t = 0; t < 3; ++t) {
        floatx4 acc = {0, 0, 0, 0};
        short8 A0 = W2T8[(t * 16 + n16) * 8 + q];
        short8 A1 = W2T8[(t * 16 + n16) * 8 + 4 + q];
        acc = __builtin_amdgcn_mfma_f32_16x16x32_bf16(A0, h1a, acc, 0, 0, 0);
        acc = __builtin_amdgcn_mfma_f32_16x16x32_bf16(A1, h1b, acc, 0, 0, 0);
        int mc = t * 16 + q * 4;
        if (mc < 40) {
            float4 bv = *(const float4*)(b2 + mc);
            float rx = acc[0] + bv.x, ry = acc[1] + bv.y;
            float rz = acc[2] + bv.z, rw = acc[3] + bv.w;
            size_t idx = (size_t)node * 10 + t * 4 + q;   // node-major quad slot
            ((float4*)h0)[idx] = make_float4(0.1f * rx, 0.1f * ry, 0.1f * rz, 0.1f * rw);
            ushort4 pk;
            pk.x = (unsigned short)bf16_rne(iv * rx);
            pk.y = (unsigned short)bf16_rne(iv * ry);
            pk.z = (unsigned short)bf16_rne(iv * rz);
            pk.w = (unsigned short)bf16_rne(iv * rw);
            u0[idx] = pk;
        }
    }
}

// ---------------- one APPNP hop, bf16 u, half-ordered, 8-deep pipelined ----------
// Thread = (node d, quad q), gid = d*10+q. Per-half avg in-degree = 8, so the
// unroll-8 {8 idx loads -> 8 gathers} pipeline actually fills (8 outstanding
// loads/thread vs 4 before). Each half's u-slice = 4 MB = per-XCD L2.
// Index loads: consecutive d in a wave -> one 64B line per load instr.
__global__ __launch_bounds__(256) void hop_kernel(
    const ushort4* __restrict__ ucur, const float4* __restrict__ h0,
    const int* __restrict__ cnt, const unsigned short* __restrict__ csr2h,
    const float* __restrict__ inv_in, const float* __restrict__ inv_out,
    ushort4* __restrict__ unew, float4* __restrict__ outf, int last)
{
    int gid = blockIdx.x * 256 + threadIdx.x;
    if (gid >= 10 * N_NODES) return;
    int d = gid / 10;
    int q = gid - d * 10;

    float4 acc = make_float4(0.f, 0.f, 0.f, 0.f);
    const ushort4* uq = ucur + q;

    #pragma unroll
    for (int p = 0; p < NPASS; ++p) {
        const unsigned short* col = csr2h + (size_t)(p * CAP_H) * N_NODES + d;
        int len = cnt[p * N_NODES + d];
        if (len > CAP_H) len = CAP_H;
        int sbase = p * (QH * 10);     // half-base in ushort4 units
        int j = 0;
        for (; j + 8 <= len; j += 8) {
            int t0 = col[(size_t)(j + 0) * N_NODES];
            int t1 = col[(size_t)(j + 1) * N_NODES];
            int t2 = col[(size_t)(j + 2) * N_NODES];
            int t3 = col[(size_t)(j + 3) * N_NODES];
            int t4 = col[(size_t)(j + 4) * N_NODES];
            int t5 = col[(size_t)(j + 5) * N_NODES];
            int t6 = col[(size_t)(j + 6) * N_NODES];
            int t7 = col[(size_t)(j + 7) * N_NODES];
            ushort4 v0 = uq[sbase + t0 * 10];
            ushort4 v1 = uq[sbase + t1 * 10];
            ushort4 v2 = uq[sbase + t2 * 10];
            ushort4 v3 = uq[sbase + t3 * 10];
            ushort4 v4 = uq[sbase + t4 * 10];
            ushort4 v5 = uq[sbase + t5 * 10];
            ushort4 v6 = uq[sbase + t6 * 10];
            ushort4 v7 = uq[sbase + t7 * 10];
            acc.x += ((bf2f(v0.x) + bf2f(v1.x)) + (bf2f(v2.x) + bf2f(v3.x)))
                   + ((bf2f(v4.x) + bf2f(v5.x)) + (bf2f(v6.x) + bf2f(v7.x)));
            acc.y += ((bf2f(v0.y) + bf2f(v1.y)) + (bf2f(v2.y) + bf2f(v3.y)))
                   + ((bf2f(v4.y) + bf2f(v5.y)) + (bf2f(v6.y) + bf2f(v7.y)));
            acc.z += ((bf2f(v0.z) + bf2f(v1.z)) + (bf2f(v2.z) + bf2f(v3.z)))
                   + ((bf2f(v4.z) + bf2f(v5.z)) + (bf2f(v6.z) + bf2f(v7.z)));
            acc.w += ((bf2f(v0.w) + bf2f(v1.w)) + (bf2f(v2.w) + bf2f(v3.w)))
                   + ((bf2f(v4.w) + bf2f(v5.w)) + (bf2f(v6.w) + bf2f(v7.w)));
        }
        for (; j + 4 <= len; j += 4) {
            int t0 = col[(size_t)(j + 0) * N_NODES];
            int t1 = col[(size_t)(j + 1) * N_NODES];
            int t2 = col[(size_t)(j + 2) * N_NODES];
            int t3 = col[(size_t)(j + 3) * N_NODES];
            ushort4 v0 = uq[sbase + t0 * 10];
            ushort4 v1 = uq[sbase + t1 * 10];
            ushort4 v2 = uq[sbase + t2 * 10];
            ushort4 v3 = uq[sbase + t3 * 10];
            acc.x += (bf2f(v0.x) + bf2f(v1.x)) + (bf2f(v2.x) + bf2f(v3.x));
            acc.y += (bf2f(v0.y) + bf2f(v1.y)) + (bf2f(v2.y) + bf2f(v3.y));
            acc.z += (bf2f(v0.z) + bf2f(v1.z)) + (bf2f(v2.z) + bf2f(v3.z));
            acc.w += (bf2f(v0.w) + bf2f(v1.w)) + (bf2f(v2.w) + bf2f(v3.w));
        }
        for (; j < len; ++j) {
            int t = col[(size_t)j * N_NODES];
            ushort4 v = uq[sbase + t * 10];
            acc.x += bf2f(v.x); acc.y += bf2f(v.y);
            acc.z += bf2f(v.z); acc.w += bf2f(v.w);
        }
    }

    float4 h0v = h0[gid];                 // pre-scaled 0.1*h0, f32
    float wi = 0.9f * inv_in[d];
    float4 res = make_float4(h0v.x + wi * acc.x, h0v.y + wi * acc.y,
                             h0v.z + wi * acc.z, h0v.w + wi * acc.w);
    if (last) {
        outf[gid] = res;                  // final hop: f32, node-major
    } else {
        float io = inv_out[d];
        ushort4 pk;
        pk.x = (unsigned short)bf16_rne(io * res.x);
        pk.y = (unsigned short)bf16_rne(io * res.y);
        pk.z = (unsigned short)bf16_rne(io * res.z);
        pk.w = (unsigned short)bf16_rne(io * res.w);
        unew[gid] = pk;
    }
}

extern "C" void kernel_launch(void* const* d_in, const int* in_sizes, int n_in,
                              void* d_out, int out_size, void* d_ws, size_t ws_size,
                              hipStream_t stream) {
    const float* x  = (const float*)d_in[0];
    const int*   ei = (const int*)d_in[1];
    const int*   src = ei;
    const int*   dst = ei + N_EDGES;
    const float* Wb = (const float*)d_in[2];
    const float* bb = (const float*)d_in[3];
    const float* W1 = (const float*)d_in[4];
    const float* b1 = (const float*)d_in[5];
    const float* W2 = (const float*)d_in[6];
    const float* b2 = (const float*)d_in[7];

    float* out_adj    = (float*)d_out;
    float* out_scores = (float*)d_out + 4000000;

    float* h0      = (float*)d_ws;                      // 4,000,000 f (0.1*h0, f32)
    ushort* ubfA   = (ushort*)(h0 + 4000000);           // 4,000,000 bf16 (u ping A)
    ushort* ubfB   = ubfA + 4000000;                    // 4,000,000 bf16 (u ping B)
    int* deg_out   = (int*)(ubfB + 4000000);            // N
    int* cnt       = deg_out + N_NODES;                 // 2*N (per-half in-degree)
    float* inv_o   = (float*)(cnt + 2 * N_NODES);       // N
    float* inv_i   = inv_o + N_NODES;                   // N
    unsigned short* csr2h = (unsigned short*)(inv_i + N_NODES);  // 2*CAP_H*N ushort
    short* WT      = (short*)(csr2h + (size_t)NPASS * CAP_H * N_NODES);
    short* W1T     = WT + 48 * 512;
    short* W2T     = W1T + 64 * 64;

    hipMemsetAsync(deg_out, 0, 3 * N_NODES * sizeof(int), stream);

    wt_kernel<<<96, 256, 0, stream>>>(Wb, W1, W2, WT, W1T, W2T);
    mega_kernel<<<BUILD_BLKS + SCORES_BLKS, 256, 0, stream>>>(
        x, (const short8*)WT, bb, out_scores,
        src, dst, deg_out, cnt, csr2h);
    inv_kernel<<<NB1, 256, 0, stream>>>(deg_out, cnt, inv_o, inv_i);

    mlp_kernel<<<1250, 320, 0, stream>>>(
        out_scores, (const short8*)W1T, b1, (const short8*)W2T, b2,
        h0, (ushort4*)ubfA, inv_o);

    // Ping-pong: even k reads A writes B, odd k reads B writes A.
    // k=9 (odd) reads B, finalizes f32 into out_adj.
    int nblk = (10 * N_NODES + 255) / 256;
    for (int k = 0; k < 10; ++k) {
        const ushort4* cur = (const ushort4*)((k & 1) ? ubfB : ubfA);
        ushort4* nxt       = (ushort4*)((k & 1) ? ubfA : ubfB);
        int last = (k == 9);
        hop_kernel<<<nblk, 256, 0, stream>>>(
            cur, (const float4*)h0, cnt, csr2h,
            inv_i, inv_o, nxt, (float4*)out_adj, last);
    }
}